// Round 1
// baseline (1215.608 us; speedup 1.0000x reference)
//
#include <hip/hip_runtime.h>
#include <math.h>

#define Bb 16
#define Cc 256
#define Nn 1024
#define Mm 256
#define NHh 8
#define HDd 32
#define HIDh 24
#define NMs (Nn*Mm)
#define CHUNK 4
#define EPSf 1e-5f
#define SCALEf 0.17677669529663687f   // 1/sqrt(32)

__device__ __forceinline__ float wave_sum(float v){
#pragma unroll
  for (int off=32; off; off>>=1) v += __shfl_xor(v, off, 64);
  return v;
}
__device__ __forceinline__ float wave_max(float v){
#pragma unroll
  for (int off=32; off; off>>=1) v = fmaxf(v, __shfl_xor(v, off, 64));
  return v;
}
__device__ __forceinline__ float swish_(float x){ return x / (1.f + __expf(-x)); }

// ------------- GEMM: out[b,i,j] = sum_k A[b,k,i]*W[j,k] (+bias) -------------
// MODE 0: O1 = qh[b,h,i,d]  (j=h*32+d)
// MODE 1: O1 = k[b,h,i,d], O2 = v[b,h,i,d]  (j in [0,512))
// MODE 2: O1[b*256+j][i] = val + bias[j]   (final output)
template<int MODE>
__launch_bounds__(256)
__global__ void gemm_tn(const float* __restrict__ A, const float* __restrict__ W,
                        const float* __restrict__ bias, float* __restrict__ O1,
                        float* __restrict__ O2, int Kdim, long sAb, int sAk, int sAi)
{
  __shared__ __align__(16) float As[16][68];
  __shared__ __align__(16) float Ws[16][68];
  const int b  = blockIdx.z;
  const int i0 = blockIdx.x * 64;
  const int j0 = blockIdx.y * 64;
  const int tid = threadIdx.x;
  const int tx = tid & 15, ty = tid >> 4;
  const float* Ab = A + (long)b * sAb;
  float acc[4][4] = {};
  for (int k0 = 0; k0 < Kdim; k0 += 16) {
#pragma unroll
    for (int t = 0; t < 4; t++) {
      int idx = tid + t * 256;
      int kk, ii;
      if (sAi == 1) { kk = idx >> 6; ii = idx & 63; }
      else          { ii = idx >> 4; kk = idx & 15; }
      As[kk][ii] = Ab[(long)(k0 + kk) * sAk + (long)(i0 + ii) * sAi];
    }
#pragma unroll
    for (int t = 0; t < 4; t++) {
      int idx = tid + t * 256;
      int jj = idx & 63, kk = idx >> 6;
      Ws[kk][jj] = W[(long)(j0 + jj) * Kdim + (k0 + kk)];
    }
    __syncthreads();
#pragma unroll
    for (int kk = 0; kk < 16; kk++) {
      const float4 av = *(const float4*)&As[kk][tx * 4];
      const float4 wv = *(const float4*)&Ws[kk][ty * 4];
      const float a4[4] = {av.x, av.y, av.z, av.w};
      const float w4[4] = {wv.x, wv.y, wv.z, wv.w};
#pragma unroll
      for (int u = 0; u < 4; u++)
#pragma unroll
        for (int v = 0; v < 4; v++)
          acc[u][v] = fmaf(a4[u], w4[v], acc[u][v]);
    }
    __syncthreads();
  }
#pragma unroll
  for (int u = 0; u < 4; u++) {
    const int i = i0 + tx * 4 + u;
#pragma unroll
    for (int v = 0; v < 4; v++) {
      const int j = j0 + ty * 4 + v;
      float val = acc[u][v];
      if (MODE == 0) {
        int h = j >> 5, d = j & 31;
        O1[(((long)b * NHh + h) * Nn + i) * HDd + d] = val;
      } else if (MODE == 1) {
        int two = j >> 8, jj = j & 255;
        int h = jj >> 5, d = jj & 31;
        float* p = two ? O2 : O1;
        p[(((long)b * NHh + h) * Mm + i) * HDd + d] = val;
      } else {
        O1[((long)b * Cc + j) * Nn + i] = val + bias[j];
      }
    }
  }
}

// ------------- sv[b,h,d] = sum_m v[b,h,m,d] -------------
__launch_bounds__(256)
__global__ void compute_sv(const float* __restrict__ vb, float* __restrict__ sv)
{
  __shared__ float red[256];
  const int bh = blockIdx.x, tid = threadIdx.x;
  const int d = tid & 31, ch = tid >> 5;
  const float* vp = vb + (long)bh * Mm * HDd;
  float s = 0.f;
  for (int m = ch; m < Mm; m += 8) s += vp[m * HDd + d];
  red[tid] = s;
  __syncthreads();
  if (tid < 32) {
    float t = 0.f;
#pragma unroll
    for (int cc = 0; cc < 8; cc++) t += red[cc * 32 + tid];
    sv[(long)bh * HDd + tid] = t;
  }
}

// ------------- scores + softmax: attn[b,h,n,m] -------------
__launch_bounds__(256)
__global__ void attn_softmax(const float* __restrict__ qh, const float* __restrict__ kb,
                             const float* __restrict__ rpb, float* __restrict__ attn)
{
  __shared__ float Ks[Mm][HDd + 1];   // +1 pad: stride-33 -> conflict-free
  __shared__ float qs[16][HDd];
  const int b = blockIdx.z, h = blockIdx.y, n0 = blockIdx.x * 16;
  const int tid = threadIdx.x;
  const float* kp = kb + ((long)b * NHh + h) * Mm * HDd;
  for (int idx = tid; idx < Mm * HDd; idx += 256)
    Ks[idx >> 5][idx & 31] = kp[idx];
  const float* qp = qh + (((long)b * NHh + h) * Nn + n0) * HDd;
  for (int idx = tid; idx < 16 * HDd; idx += 256)
    qs[idx >> 5][idx & 31] = qp[idx];
  __syncthreads();
  const int lane = tid & 63, wid = tid >> 6;
  for (int it = 0; it < 4; it++) {
    const int r = it * 4 + wid;
    const int n = n0 + r;
    float s[4];
#pragma unroll
    for (int j = 0; j < 4; j++) {
      const int m = lane + j * 64;
      float acc = 0.f;
#pragma unroll
      for (int d = 0; d < HDd; d++) acc = fmaf(qs[r][d], Ks[m][d], acc);
      s[j] = acc * SCALEf + rpb[(long)n * Mm + m];
    }
    float mx = fmaxf(fmaxf(s[0], s[1]), fmaxf(s[2], s[3]));
    mx = wave_max(mx);
    float e[4], sum = 0.f;
#pragma unroll
    for (int j = 0; j < 4; j++) { e[j] = __expf(s[j] - mx); sum += e[j]; }
    sum = wave_sum(sum);
    const float inv = 1.f / sum;
    float* ap = attn + (((long)b * NHh + h) * Nn + n) * Mm;
#pragma unroll
    for (int j = 0; j < 4; j++) ap[lane + j * 64] = e[j] * inv;
  }
}

// ------------- K3: 1x1 expand, gn1 stats (sum, sumsq per (b,group)) -------------
__launch_bounds__(256)
__global__ void expand_stats(const float* __restrict__ attn, const float* __restrict__ Wexp,
                             float* __restrict__ stats1, int b0)
{
  __shared__ float we[HIDh][NHh];
  __shared__ float red6[6][4];
  const int tid = threadIdx.x;
  const int b = b0 + blockIdx.y;
  if (tid < HIDh * NHh) ((float*)we)[tid] = Wexp[tid];
  __syncthreads();
  const float* ab = attn + (long)b * NHh * NMs;
  float s[3] = {}, sq[3] = {};
  for (int t = 0; t < 4; t++) {
    const long p = (long)blockIdx.x * 1024 + t * 256 + tid;
    float a[NHh];
#pragma unroll
    for (int h = 0; h < NHh; h++) a[h] = ab[(long)h * NMs + p];
#pragma unroll
    for (int c = 0; c < HIDh; c++) {
      float x = 0.f;
#pragma unroll
      for (int h = 0; h < NHh; h++) x = fmaf(we[c][h], a[h], x);
      s[c >> 3] += x; sq[c >> 3] = fmaf(x, x, sq[c >> 3]);
    }
  }
  const int lane = tid & 63, wid = tid >> 6;
#pragma unroll
  for (int g = 0; g < 3; g++) {
    float vs = wave_sum(s[g]);
    float vq = wave_sum(sq[g]);
    if (lane == 0) { red6[g * 2][wid] = vs; red6[g * 2 + 1][wid] = vq; }
  }
  __syncthreads();
  if (tid < 6) {
    float t = red6[tid][0] + red6[tid][1] + red6[tid][2] + red6[tid][3];
    atomicAdd(&stats1[b * 6 + tid], t);
  }
}

// ------------- K4: expand again, gn1 normalize + swish -> x1n -------------
__launch_bounds__(256)
__global__ void expand_norm(const float* __restrict__ attn, const float* __restrict__ Wexp,
                            const float* __restrict__ g1, const float* __restrict__ b1,
                            const float* __restrict__ stats1, float* __restrict__ x1n, int b0)
{
  __shared__ float we[HIDh][NHh];
  __shared__ float gg[HIDh], bbv[HIDh], mean[3], rs[3];
  const int tid = threadIdx.x;
  const int bc = blockIdx.y, b = b0 + bc;
  const long p = (long)blockIdx.x * 256 + tid;
  if (tid < 192) ((float*)we)[tid] = Wexp[tid];
  if (tid >= 192 && tid < 216) gg[tid - 192] = g1[tid - 192];
  if (tid >= 216 && tid < 240) bbv[tid - 216] = b1[tid - 216];
  if (tid >= 240 && tid < 243) {
    const int g = tid - 240;
    const float cnt = 8.f * NMs;
    float mu = stats1[b * 6 + g * 2] / cnt;
    float var = stats1[b * 6 + g * 2 + 1] / cnt - mu * mu;
    mean[g] = mu; rs[g] = rsqrtf(var + EPSf);
  }
  __syncthreads();
  float a[NHh];
  const float* ab = attn + (long)b * NHh * NMs;
#pragma unroll
  for (int h = 0; h < NHh; h++) a[h] = ab[(long)h * NMs + p];
  float* xp = x1n + (long)bc * HIDh * NMs + p;
#pragma unroll
  for (int c = 0; c < HIDh; c++) {
    float x = 0.f;
#pragma unroll
    for (int h = 0; h < NHh; h++) x = fmaf(we[c][h], a[h], x);
    const int g = c >> 3;
    float xn = (x - mean[g]) * rs[g] * gg[c] + bbv[c];
    xp[(long)c * NMs] = swish_(xn);
  }
}

// ------------- K5: depthwise 3x3 over (n,m), gn2 stats per (b,c) -------------
__launch_bounds__(256)
__global__ void dwconv_stats(const float* __restrict__ x1n, const float* __restrict__ Wdw,
                             float* __restrict__ stats2c, int b0)
{
  __shared__ float red2[2][4];
  const int tid = threadIdx.x;               // mm
  const int cz = blockIdx.y;
  const int bc = cz / HIDh, c = cz % HIDh;
  const int b = b0 + bc;
  const int n0 = blockIdx.x * 4;
  const float* xp = x1n + ((long)bc * HIDh + c) * NMs;
  float w[9];
#pragma unroll
  for (int t = 0; t < 9; t++) w[t] = Wdw[c * 9 + t];
  const int mm = tid;
  float win[6][3];
#pragma unroll
  for (int r = 0; r < 6; r++) {
    const int nn = n0 - 1 + r;
    const bool vr = (nn >= 0 && nn < Nn);
    const float* row = xp + (long)nn * Mm;
    win[r][0] = (vr && mm > 0)      ? row[mm - 1] : 0.f;
    win[r][1] = vr                  ? row[mm]     : 0.f;
    win[r][2] = (vr && mm < Mm - 1) ? row[mm + 1] : 0.f;
  }
  float s = 0.f, sq = 0.f;
#pragma unroll
  for (int t = 0; t < 4; t++) {
    float y = 0.f;
#pragma unroll
    for (int kh = 0; kh < 3; kh++)
#pragma unroll
      for (int kw = 0; kw < 3; kw++)
        y = fmaf(win[t + kh][kw], w[kh * 3 + kw], y);
    s += y; sq = fmaf(y, y, sq);
  }
  const int lane = tid & 63, wid = tid >> 6;
  s = wave_sum(s); sq = wave_sum(sq);
  if (lane == 0) { red2[0][wid] = s; red2[1][wid] = sq; }
  __syncthreads();
  if (tid < 2) {
    float t = red2[tid][0] + red2[tid][1] + red2[tid][2] + red2[tid][3];
    atomicAdd(&stats2c[((long)b * HIDh + c) * 2 + tid], t);
  }
}

// ------------- K6: conv again + gn2 + swish + 1x1 reduce -> a2, gn3 stats -------------
__launch_bounds__(256)
__global__ void dwconv_fuse(const float* __restrict__ x1n, const float* __restrict__ Wdw,
                            const float* __restrict__ g2, const float* __restrict__ b2,
                            const float* __restrict__ Wred, const float* __restrict__ stats2c,
                            float* __restrict__ a2g, float* __restrict__ stats3, int b0)
{
  __shared__ float wdw[HIDh][9];
  __shared__ float wred[NHh][HIDh];
  __shared__ float gg[HIDh], bbv[HIDh], mean2[3], rs2[3];
  __shared__ float red2[2][4];
  const int tid = threadIdx.x;               // mm
  const int bc = blockIdx.y, b = b0 + bc;
  const int n0 = blockIdx.x * 4;
  if (tid < 216) ((float*)wdw)[tid] = Wdw[tid];
  if (tid < 192) ((float*)wred)[tid] = Wred[tid];
  if (tid < HIDh) { gg[tid] = g2[tid]; bbv[tid] = b2[tid]; }
  if (tid < 3) {
    float s = 0.f, sq = 0.f;
#pragma unroll
    for (int cc = 0; cc < 8; cc++) {
      s  += stats2c[((long)b * HIDh + tid * 8 + cc) * 2];
      sq += stats2c[((long)b * HIDh + tid * 8 + cc) * 2 + 1];
    }
    const float cnt = 8.f * NMs;
    float mu = s / cnt;
    float var = sq / cnt - mu * mu;
    mean2[tid] = mu; rs2[tid] = rsqrtf(var + EPSf);
  }
  __syncthreads();
  const int mm = tid;
  float acc[4][NHh] = {};
  for (int c = 0; c < HIDh; c++) {
    const float* xp = x1n + ((long)bc * HIDh + c) * NMs;
    float win[6][3];
#pragma unroll
    for (int r = 0; r < 6; r++) {
      const int nn = n0 - 1 + r;
      const bool vr = (nn >= 0 && nn < Nn);
      const float* row = xp + (long)nn * Mm;
      win[r][0] = (vr && mm > 0)      ? row[mm - 1] : 0.f;
      win[r][1] = vr                  ? row[mm]     : 0.f;
      win[r][2] = (vr && mm < Mm - 1) ? row[mm + 1] : 0.f;
    }
    const int g = c >> 3;
    const float gc = gg[c], bec = bbv[c], mu = mean2[g], r2 = rs2[g];
#pragma unroll
    for (int t = 0; t < 4; t++) {
      float y = 0.f;
#pragma unroll
      for (int kh = 0; kh < 3; kh++)
#pragma unroll
        for (int kw = 0; kw < 3; kw++)
          y = fmaf(win[t + kh][kw], wdw[c][kh * 3 + kw], y);
      float xn = (y - mu) * r2 * gc + bec;
      float sw = swish_(xn);
#pragma unroll
      for (int h = 0; h < NHh; h++) acc[t][h] = fmaf(wred[h][c], sw, acc[t][h]);
    }
  }
  float s3 = 0.f, q3 = 0.f;
#pragma unroll
  for (int t = 0; t < 4; t++)
#pragma unroll
    for (int h = 0; h < NHh; h++) {
      const float v2 = acc[t][h];
      s3 += v2; q3 = fmaf(v2, v2, q3);
      a2g[(((long)b * NHh + h) * Nn + (n0 + t)) * Mm + mm] = v2;
    }
  const int lane = tid & 63, wid = tid >> 6;
  s3 = wave_sum(s3); q3 = wave_sum(q3);
  if (lane == 0) { red2[0][wid] = s3; red2[1][wid] = q3; }
  __syncthreads();
  if (tid < 2) {
    float t = red2[tid][0] + red2[tid][1] + red2[tid][2] + red2[tid][3];
    atomicAdd(&stats3[b * 2 + tid], t);
  }
}

// ------------- K7: gn3 (folded affine) + PV -> o[b,n,c] -------------
__launch_bounds__(256)
__global__ void pv_out(const float* __restrict__ a2, const float* __restrict__ vb,
                       const float* __restrict__ sv, const float* __restrict__ stats3,
                       const float* __restrict__ g3, const float* __restrict__ b3,
                       float* __restrict__ o)
{
  __shared__ float a2s[8][Mm];
  const int b = blockIdx.z, h = blockIdx.y, n0 = blockIdx.x * 8;
  const int tid = threadIdx.x;
  const float* ap = a2 + (((long)b * NHh + h) * Nn + n0) * Mm;
#pragma unroll
  for (int t = 0; t < 8; t++) {
    const int idx = tid + t * 256;
    a2s[idx >> 8][idx & 255] = ap[idx];
  }
  __syncthreads();
  const float cnt = (float)(NHh * NMs);
  const float mu = stats3[b * 2] / cnt;
  const float var = stats3[b * 2 + 1] / cnt - mu * mu;
  const float r3 = rsqrtf(var + EPSf);
  const float alpha = r3 * g3[h];
  const float beta = b3[h] - mu * alpha;
  const int d = tid & 31, r = tid >> 5;
  const float* vp = vb + ((long)b * NHh + h) * Mm * HDd;
  float acc = 0.f;
#pragma unroll 4
  for (int m = 0; m < Mm; m++) acc = fmaf(a2s[r][m], vp[m * HDd + d], acc);
  const float outv = alpha * acc + beta * sv[((long)b * NHh + h) * HDd + d];
  o[((long)b * Nn + (n0 + r)) * Cc + h * HDd + d] = outv;
}

extern "C" void kernel_launch(void* const* d_in, const int* in_sizes, int n_in,
                              void* d_out, int out_size, void* d_ws, size_t ws_size,
                              hipStream_t stream) {
  const float* q    = (const float*)d_in[0];
  const float* kv   = (const float*)d_in[1];
  const float* Wq   = (const float*)d_in[2];
  const float* Wkv  = (const float*)d_in[3];
  const float* Wp   = (const float*)d_in[4];
  const float* bp   = (const float*)d_in[5];
  const float* rpb  = (const float*)d_in[6];
  const float* Wexp = (const float*)d_in[7];
  const float* g1   = (const float*)d_in[8];
  const float* b1   = (const float*)d_in[9];
  const float* Wdw  = (const float*)d_in[10];
  const float* g2   = (const float*)d_in[11];
  const float* b2   = (const float*)d_in[12];
  const float* Wred = (const float*)d_in[13];
  const float* g3   = (const float*)d_in[14];
  const float* b3   = (const float*)d_in[15];
  float* out = (float*)d_out;

  float* ws = (float*)d_ws;
  size_t off = 0;
  auto alloc = [&](size_t n) { float* p = ws + off; off += n; return p; };
  float* attn   = alloc((size_t)Bb * NHh * NMs);        // 134.2 MB (reused for a2)
  float* x1n    = alloc((size_t)CHUNK * HIDh * NMs);    // 100.7 MB
  float* qh     = alloc((size_t)Bb * NHh * Nn * HDd);   // 16.8 MB (reused for o)
  float* kbuf   = alloc((size_t)Bb * NHh * Mm * HDd);   // 4.2 MB
  float* vbuf   = alloc((size_t)Bb * NHh * Mm * HDd);   // 4.2 MB
  float* sv     = alloc((size_t)Bb * NHh * HDd);
  float* stats1 = alloc(Bb * 6);
  float* stats2c= alloc((size_t)Bb * HIDh * 2);
  float* stats3 = alloc(Bb * 2);
  float* o = qh;

  // zero the (atomic-accumulated) stats: stats1|stats2c|stats3 are contiguous
  hipMemsetAsync(stats1, 0, (size_t)(Bb * 6 + Bb * HIDh * 2 + Bb * 2) * sizeof(float), stream);

  // q projection: qh[b,h,n,d]
  gemm_tn<0><<<dim3(Nn / 64, Cc / 64, Bb), 256, 0, stream>>>(
      q, Wq, nullptr, qh, nullptr, Cc, (long)Cc * Nn, Nn, 1);
  // kv projection: k,v[b,h,m,d]
  gemm_tn<1><<<dim3(Mm / 64, 512 / 64, Bb), 256, 0, stream>>>(
      kv, Wkv, nullptr, kbuf, vbuf, Cc, (long)Cc * Mm, Mm, 1);
  compute_sv<<<dim3(Bb * NHh), 256, 0, stream>>>(vbuf, sv);
  attn_softmax<<<dim3(Nn / 16, NHh, Bb), 256, 0, stream>>>(qh, kbuf, rpb, attn);

  for (int b0 = 0; b0 < Bb; b0 += CHUNK) {
    expand_stats<<<dim3(NMs / 1024, CHUNK), 256, 0, stream>>>(attn, Wexp, stats1, b0);
    expand_norm<<<dim3(NMs / 256, CHUNK), 256, 0, stream>>>(attn, Wexp, g1, b1, stats1, x1n, b0);
    dwconv_stats<<<dim3(Nn / 4, CHUNK * HIDh), 256, 0, stream>>>(x1n, Wdw, stats2c, b0);
    dwconv_fuse<<<dim3(Nn / 4, CHUNK), 256, 0, stream>>>(
        x1n, Wdw, g2, b2, Wred, stats2c, attn, stats3, b0);
  }

  pv_out<<<dim3(Nn / 8, NHh, Bb), 256, 0, stream>>>(attn, vbuf, sv, stats3, g3, b3, o);
  // final projection + bias, output [b, c, n]
  gemm_tn<2><<<dim3(Nn / 64, Cc / 64, Bb), 256, 0, stream>>>(
      o, Wp, bp, out, nullptr, Cc, (long)Nn * Cc, 1, Cc);
}

// Round 2
// 797.688 us; speedup vs baseline: 1.5239x; 1.5239x over previous
//
#include <hip/hip_runtime.h>
#include <math.h>

#define Bb 16
#define Cc 256
#define Nn 1024
#define Mm 256
#define NHh 8
#define HDd 32
#define HIDh 24
#define NMs (Nn*Mm)
#define CHUNK 4
#define EPSf 1e-5f
#define SCALEf 0.17677669529663687f   // 1/sqrt(32)

__device__ __forceinline__ float wave_sum(float v){
#pragma unroll
  for (int off=32; off; off>>=1) v += __shfl_xor(v, off, 64);
  return v;
}
__device__ __forceinline__ float wave_max(float v){
#pragma unroll
  for (int off=32; off; off>>=1) v = fmaxf(v, __shfl_xor(v, off, 64));
  return v;
}
__device__ __forceinline__ float swish_(float x){ return x / (1.f + __expf(-x)); }

// ------------- GEMM: out[b,i,j] = sum_k A[b,k,i]*W[j,k] (+bias) -------------
template<int MODE>
__launch_bounds__(256)
__global__ void gemm_tn(const float* __restrict__ A, const float* __restrict__ W,
                        const float* __restrict__ bias, float* __restrict__ O1,
                        float* __restrict__ O2, int Kdim, long sAb, int sAk, int sAi)
{
  __shared__ __align__(16) float As[16][68];
  __shared__ __align__(16) float Ws[16][68];
  const int b  = blockIdx.z;
  const int i0 = blockIdx.x * 64;
  const int j0 = blockIdx.y * 64;
  const int tid = threadIdx.x;
  const int tx = tid & 15, ty = tid >> 4;
  const float* Ab = A + (long)b * sAb;
  float acc[4][4] = {};
  for (int k0 = 0; k0 < Kdim; k0 += 16) {
#pragma unroll
    for (int t = 0; t < 4; t++) {
      int idx = tid + t * 256;
      int kk, ii;
      if (sAi == 1) { kk = idx >> 6; ii = idx & 63; }
      else          { ii = idx >> 4; kk = idx & 15; }
      As[kk][ii] = Ab[(long)(k0 + kk) * sAk + (long)(i0 + ii) * sAi];
    }
#pragma unroll
    for (int t = 0; t < 4; t++) {
      int idx = tid + t * 256;
      int jj = idx & 63, kk = idx >> 6;
      Ws[kk][jj] = W[(long)(j0 + jj) * Kdim + (k0 + kk)];
    }
    __syncthreads();
#pragma unroll
    for (int kk = 0; kk < 16; kk++) {
      const float4 av = *(const float4*)&As[kk][tx * 4];
      const float4 wv = *(const float4*)&Ws[kk][ty * 4];
      const float a4[4] = {av.x, av.y, av.z, av.w};
      const float w4[4] = {wv.x, wv.y, wv.z, wv.w};
#pragma unroll
      for (int u = 0; u < 4; u++)
#pragma unroll
        for (int v = 0; v < 4; v++)
          acc[u][v] = fmaf(a4[u], w4[v], acc[u][v]);
    }
    __syncthreads();
  }
#pragma unroll
  for (int u = 0; u < 4; u++) {
    const int i = i0 + tx * 4 + u;
#pragma unroll
    for (int v = 0; v < 4; v++) {
      const int j = j0 + ty * 4 + v;
      float val = acc[u][v];
      if (MODE == 0) {
        int h = j >> 5, d = j & 31;
        O1[(((long)b * NHh + h) * Nn + i) * HDd + d] = val;
      } else if (MODE == 1) {
        int two = j >> 8, jj = j & 255;
        int h = jj >> 5, d = jj & 31;
        float* p = two ? O2 : O1;
        p[(((long)b * NHh + h) * Mm + i) * HDd + d] = val;
      } else {
        O1[((long)b * Cc + j) * Nn + i] = val + bias[j];
      }
    }
  }
}

// ------------- sv[b,h,d] = sum_m v[b,h,m,d] -------------
__launch_bounds__(256)
__global__ void compute_sv(const float* __restrict__ vb, float* __restrict__ sv)
{
  __shared__ float red[256];
  const int bh = blockIdx.x, tid = threadIdx.x;
  const int d = tid & 31, ch = tid >> 5;
  const float* vp = vb + (long)bh * Mm * HDd;
  float s = 0.f;
  for (int m = ch; m < Mm; m += 8) s += vp[m * HDd + d];
  red[tid] = s;
  __syncthreads();
  if (tid < 32) {
    float t = 0.f;
#pragma unroll
    for (int cc = 0; cc < 8; cc++) t += red[cc * 32 + tid];
    sv[(long)bh * HDd + tid] = t;
  }
}

// ------------- scores + softmax: attn[b,h,n,m] -------------
// 32 rows/block; each wave handles 8 rows x 256 m (4 m per lane) jointly.
__launch_bounds__(256)
__global__ void attn_softmax(const float* __restrict__ qh, const float* __restrict__ kb,
                             const float* __restrict__ rpb, float* __restrict__ attn)
{
  __shared__ __align__(16) float Ks[Mm][36];   // stride 36: b128-aligned, 2-way max
  __shared__ __align__(16) float qs[32][36];
  const int b = blockIdx.z, h = blockIdx.y, n0 = blockIdx.x * 32;
  const int tid = threadIdx.x;
  const float* kp = kb + ((long)b * NHh + h) * Mm * HDd;
#pragma unroll
  for (int u = 0; u < 8; u++) {               // 2048 float4s
    const int f = tid + u * 256;
    const int m = f >> 3, d = (f & 7) * 4;
    *(float4*)&Ks[m][d] = *(const float4*)&kp[m * HDd + d];
  }
  const float* qp = qh + (((long)b * NHh + h) * Nn + n0) * HDd;
#pragma unroll
  for (int u = 0; u < 4; u++) {
    const int idx = tid + u * 256;
    qs[idx >> 5][idx & 31] = qp[idx];
  }
  __syncthreads();
  const int lane = tid & 63, w = tid >> 6;
  const int r0 = w * 8;
  float s[8][4] = {};
#pragma unroll
  for (int dq = 0; dq < 8; dq++) {
    float4 k4[4];
#pragma unroll
    for (int j = 0; j < 4; j++) k4[j] = *(const float4*)&Ks[lane + j * 64][dq * 4];
#pragma unroll
    for (int r = 0; r < 8; r++) {
      const float4 q4 = *(const float4*)&qs[r0 + r][dq * 4];
#pragma unroll
      for (int j = 0; j < 4; j++) {
        s[r][j] = fmaf(q4.x, k4[j].x, s[r][j]);
        s[r][j] = fmaf(q4.y, k4[j].y, s[r][j]);
        s[r][j] = fmaf(q4.z, k4[j].z, s[r][j]);
        s[r][j] = fmaf(q4.w, k4[j].w, s[r][j]);
      }
    }
  }
#pragma unroll
  for (int r = 0; r < 8; r++) {
    const int n = n0 + r0 + r;
    const float* rp = rpb + (long)n * Mm;
    float sc[4];
#pragma unroll
    for (int j = 0; j < 4; j++) sc[j] = fmaf(s[r][j], SCALEf, rp[lane + j * 64]);
    float mx = fmaxf(fmaxf(sc[0], sc[1]), fmaxf(sc[2], sc[3]));
    mx = wave_max(mx);
    float e[4], sum = 0.f;
#pragma unroll
    for (int j = 0; j < 4; j++) { e[j] = __expf(sc[j] - mx); sum += e[j]; }
    sum = wave_sum(sum);
    const float inv = 1.f / sum;
    float* ap = attn + (((long)b * NHh + h) * Nn + n) * Mm;
#pragma unroll
    for (int j = 0; j < 4; j++) ap[lane + j * 64] = e[j] * inv;
  }
}

// ------------- K3: 1x1 expand, gn1 stats (sum, sumsq per (b,group)) -------------
__launch_bounds__(256)
__global__ void expand_stats(const float* __restrict__ attn, const float* __restrict__ Wexp,
                             float* __restrict__ stats1, int b0)
{
  __shared__ float we[HIDh][NHh];
  __shared__ float red6[6][4];
  const int tid = threadIdx.x;
  const int b = b0 + blockIdx.y;
  if (tid < HIDh * NHh) ((float*)we)[tid] = Wexp[tid];
  __syncthreads();
  const float* ab = attn + (long)b * NHh * NMs;
  float s[3] = {}, sq[3] = {};
  for (int t = 0; t < 4; t++) {
    const long p = (long)blockIdx.x * 1024 + t * 256 + tid;
    float a[NHh];
#pragma unroll
    for (int h = 0; h < NHh; h++) a[h] = ab[(long)h * NMs + p];
#pragma unroll
    for (int c = 0; c < HIDh; c++) {
      float x = 0.f;
#pragma unroll
      for (int h = 0; h < NHh; h++) x = fmaf(we[c][h], a[h], x);
      s[c >> 3] += x; sq[c >> 3] = fmaf(x, x, sq[c >> 3]);
    }
  }
  const int lane = tid & 63, wid = tid >> 6;
#pragma unroll
  for (int g = 0; g < 3; g++) {
    float vs = wave_sum(s[g]);
    float vq = wave_sum(sq[g]);
    if (lane == 0) { red6[g * 2][wid] = vs; red6[g * 2 + 1][wid] = vq; }
  }
  __syncthreads();
  if (tid < 6) {
    float t = red6[tid][0] + red6[tid][1] + red6[tid][2] + red6[tid][3];
    atomicAdd(&stats1[b * 6 + tid], t);
  }
}

// ------------- K4: expand again, gn1 normalize + swish -> x1n -------------
__launch_bounds__(256)
__global__ void expand_norm(const float* __restrict__ attn, const float* __restrict__ Wexp,
                            const float* __restrict__ g1, const float* __restrict__ b1,
                            const float* __restrict__ stats1, float* __restrict__ x1n, int b0)
{
  __shared__ float we[HIDh][NHh];
  __shared__ float gg[HIDh], bbv[HIDh], mean[3], rs[3];
  const int tid = threadIdx.x;
  const int bc = blockIdx.y, b = b0 + bc;
  const long p = (long)blockIdx.x * 256 + tid;
  if (tid < 192) ((float*)we)[tid] = Wexp[tid];
  if (tid >= 192 && tid < 216) gg[tid - 192] = g1[tid - 192];
  if (tid >= 216 && tid < 240) bbv[tid - 216] = b1[tid - 216];
  if (tid >= 240 && tid < 243) {
    const int g = tid - 240;
    const float cnt = 8.f * NMs;
    float mu = stats1[b * 6 + g * 2] / cnt;
    float var = stats1[b * 6 + g * 2 + 1] / cnt - mu * mu;
    mean[g] = mu; rs[g] = rsqrtf(var + EPSf);
  }
  __syncthreads();
  float a[NHh];
  const float* ab = attn + (long)b * NHh * NMs;
#pragma unroll
  for (int h = 0; h < NHh; h++) a[h] = ab[(long)h * NMs + p];
  float* xp = x1n + (long)bc * HIDh * NMs + p;
#pragma unroll
  for (int c = 0; c < HIDh; c++) {
    float x = 0.f;
#pragma unroll
    for (int h = 0; h < NHh; h++) x = fmaf(we[c][h], a[h], x);
    const int g = c >> 3;
    float xn = (x - mean[g]) * rs[g] * gg[c] + bbv[c];
    xp[(long)c * NMs] = swish_(xn);
  }
}

// ------------- K5: depthwise 3x3 rolling, gn2 stats per (b,c). 16-row tiles ----
__launch_bounds__(256)
__global__ void dwconv_stats(const float* __restrict__ x1n, const float* __restrict__ Wdw,
                             float* __restrict__ stats2c, int b0)
{
  __shared__ float red2[2][4];
  const int tid = threadIdx.x;               // mm
  const int cz = blockIdx.y;
  const int bc = cz / HIDh, c = cz % HIDh;
  const int b = b0 + bc;
  const int n0 = blockIdx.x * 16;
  const float* xp = x1n + ((long)bc * HIDh + c) * NMs;
  float w[9];
#pragma unroll
  for (int t = 0; t < 9; t++) w[t] = Wdw[c * 9 + t];
  const int mm = tid;
  float c0 = 0.f, c1 = 0.f, s = 0.f, sq = 0.f;
#pragma unroll
  for (int r = -1; r <= 16; r++) {
    const int nn = n0 + r;
    float a = 0.f, bcen = 0.f, cr = 0.f;
    if (nn >= 0 && nn < Nn) {
      const float* row = xp + (long)nn * Mm;
      bcen = row[mm];
      a  = (mm > 0)      ? row[mm - 1] : 0.f;
      cr = (mm < Mm - 1) ? row[mm + 1] : 0.f;
    }
    const float u0 = a * w[0] + bcen * w[1] + cr * w[2];
    const float u1 = a * w[3] + bcen * w[4] + cr * w[5];
    const float u2 = a * w[6] + bcen * w[7] + cr * w[8];
    if (r >= 1) { const float y = c1 + u2; s += y; sq = fmaf(y, y, sq); }
    c1 = c0 + u1; c0 = u0;
  }
  const int lane = tid & 63, wid = tid >> 6;
  s = wave_sum(s); sq = wave_sum(sq);
  if (lane == 0) { red2[0][wid] = s; red2[1][wid] = sq; }
  __syncthreads();
  if (tid < 2) {
    float t = red2[tid][0] + red2[tid][1] + red2[tid][2] + red2[tid][3];
    atomicAdd(&stats2c[((long)b * HIDh + c) * 2 + tid], t);
  }
}

// ------------- K6: conv (rolling, 8-row tiles) + gn2 + swish + 1x1 reduce -----
__launch_bounds__(256)
__global__ void dwconv_fuse(const float* __restrict__ x1n, const float* __restrict__ Wdw,
                            const float* __restrict__ g2, const float* __restrict__ b2,
                            const float* __restrict__ Wred, const float* __restrict__ stats2c,
                            float* __restrict__ a2g, float* __restrict__ stats3, int b0)
{
  __shared__ float wdw[HIDh][9];
  __shared__ float wred[NHh][HIDh];
  __shared__ float gg[HIDh], bbv[HIDh], mean2[3], rs2[3];
  __shared__ float red2[2][4];
  const int tid = threadIdx.x;               // mm
  const int bc = blockIdx.y, b = b0 + bc;
  const int n0 = blockIdx.x * 8;
  if (tid < 216) ((float*)wdw)[tid] = Wdw[tid];
  if (tid < 192) ((float*)wred)[tid] = Wred[tid];
  if (tid < HIDh) { gg[tid] = g2[tid]; bbv[tid] = b2[tid]; }
  if (tid < 3) {
    float s = 0.f, sq = 0.f;
#pragma unroll
    for (int cc = 0; cc < 8; cc++) {
      s  += stats2c[((long)b * HIDh + tid * 8 + cc) * 2];
      sq += stats2c[((long)b * HIDh + tid * 8 + cc) * 2 + 1];
    }
    const float cnt = 8.f * NMs;
    float mu = s / cnt;
    float var = sq / cnt - mu * mu;
    mean2[tid] = mu; rs2[tid] = rsqrtf(var + EPSf);
  }
  __syncthreads();
  const int mm = tid;
  float acc[8][NHh] = {};
  for (int c = 0; c < HIDh; c++) {
    const float* xp = x1n + ((long)bc * HIDh + c) * NMs;
    const int g = c >> 3;
    const float gc = gg[c], bec = bbv[c], mu = mean2[g], r2 = rs2[g];
    float w0 = wdw[c][0], w1 = wdw[c][1], w2 = wdw[c][2];
    float w3 = wdw[c][3], w4 = wdw[c][4], w5 = wdw[c][5];
    float w6 = wdw[c][6], w7 = wdw[c][7], w8 = wdw[c][8];
    float wr[NHh];
#pragma unroll
    for (int h = 0; h < NHh; h++) wr[h] = wred[h][c];
    float cr0 = 0.f, cr1 = 0.f;
#pragma unroll
    for (int r = -1; r <= 8; r++) {
      const int nn = n0 + r;
      float a = 0.f, bcen = 0.f, cright = 0.f;
      if (nn >= 0 && nn < Nn) {
        const float* row = xp + (long)nn * Mm;
        bcen = row[mm];
        a      = (mm > 0)      ? row[mm - 1] : 0.f;
        cright = (mm < Mm - 1) ? row[mm + 1] : 0.f;
      }
      const float u0 = a * w0 + bcen * w1 + cright * w2;
      const float u1 = a * w3 + bcen * w4 + cright * w5;
      const float u2 = a * w6 + bcen * w7 + cright * w8;
      if (r >= 1) {
        const float y = cr1 + u2;
        const float xn = (y - mu) * r2 * gc + bec;
        const float sw = swish_(xn);
#pragma unroll
        for (int h = 0; h < NHh; h++) acc[r - 1][h] = fmaf(wr[h], sw, acc[r - 1][h]);
      }
      cr1 = cr0 + u1; cr0 = u0;
    }
  }
  float s3 = 0.f, q3 = 0.f;
#pragma unroll
  for (int t = 0; t < 8; t++)
#pragma unroll
    for (int h = 0; h < NHh; h++) {
      const float v2 = acc[t][h];
      s3 += v2; q3 = fmaf(v2, v2, q3);
      a2g[(((long)b * NHh + h) * Nn + (n0 + t)) * Mm + mm] = v2;
    }
  const int lane = tid & 63, wid = tid >> 6;
  s3 = wave_sum(s3); q3 = wave_sum(q3);
  if (lane == 0) { red2[0][wid] = s3; red2[1][wid] = q3; }
  __syncthreads();
  if (tid < 2) {
    float t = red2[tid][0] + red2[tid][1] + red2[tid][2] + red2[tid][3];
    atomicAdd(&stats3[b * 2 + tid], t);
  }
}

// ------------- K7: gn3 (folded affine) + PV, register-tiled GEMM -------------
// Per (b,h): out[256-row tile][32] = A[256x256] * V[256x32]. 4x8 microtile.
__launch_bounds__(256)
__global__ void pv_out(const float* __restrict__ a2, const float* __restrict__ vb,
                       const float* __restrict__ sv, const float* __restrict__ stats3,
                       const float* __restrict__ g3, const float* __restrict__ b3,
                       float* __restrict__ o)
{
  __shared__ __align__(16) float As[16 * 260];   // As[k][row], stride 260
  __shared__ __align__(16) float Vs[Mm * HDd];   // Vs[m][d], flat
  const int b = blockIdx.z, h = blockIdx.y, n0 = blockIdx.x * 256;
  const int tid = threadIdx.x;
  const float* vp = vb + ((long)b * NHh + h) * Mm * HDd;
#pragma unroll
  for (int u = 0; u < 8; u++) {
    const int f = tid + u * 256;
    ((float4*)Vs)[f] = ((const float4*)vp)[f];
  }
  const float* ap = a2 + (((long)b * NHh + h) * Nn + n0) * Mm;
  const int tx = tid & 63, ty = tid >> 6;
  float acc[4][8] = {};
  for (int k0 = 0; k0 < Mm; k0 += 16) {
    __syncthreads();   // protect As reuse (and Vs on first iter)
#pragma unroll
    for (int u = 0; u < 4; u++) {
      const int f = tid + u * 256;          // 1024 float4s = 256 rows x 4 kq
      const int r = f >> 2, kq = f & 3;
      const float4 a4 = *(const float4*)&ap[(long)r * Mm + k0 + kq * 4];
      As[(kq * 4 + 0) * 260 + r] = a4.x;
      As[(kq * 4 + 1) * 260 + r] = a4.y;
      As[(kq * 4 + 2) * 260 + r] = a4.z;
      As[(kq * 4 + 3) * 260 + r] = a4.w;
    }
    __syncthreads();
#pragma unroll
    for (int k = 0; k < 16; k++) {
      const float4 a4 = *(const float4*)&As[k * 260 + tx * 4];
      const float4 v0 = *(const float4*)&Vs[(k0 + k) * HDd + ty * 8];
      const float4 v1 = *(const float4*)&Vs[(k0 + k) * HDd + ty * 8 + 4];
      const float av[4] = {a4.x, a4.y, a4.z, a4.w};
      const float vv[8] = {v0.x, v0.y, v0.z, v0.w, v1.x, v1.y, v1.z, v1.w};
#pragma unroll
      for (int u = 0; u < 4; u++)
#pragma unroll
        for (int v = 0; v < 8; v++)
          acc[u][v] = fmaf(av[u], vv[v], acc[u][v]);
    }
  }
  const float cnt = (float)(NHh * NMs);
  const float mu = stats3[b * 2] / cnt;
  const float var = stats3[b * 2 + 1] / cnt - mu * mu;
  const float r3 = rsqrtf(var + EPSf);
  const float alpha = r3 * g3[h];
  const float beta = b3[h] - mu * alpha;
  float svv[8];
#pragma unroll
  for (int v = 0; v < 8; v++) svv[v] = sv[((long)b * NHh + h) * HDd + ty * 8 + v];
#pragma unroll
  for (int u = 0; u < 4; u++) {
    const int n = n0 + tx * 4 + u;
    float4 o0, o1;
    o0.x = alpha * acc[u][0] + beta * svv[0];
    o0.y = alpha * acc[u][1] + beta * svv[1];
    o0.z = alpha * acc[u][2] + beta * svv[2];
    o0.w = alpha * acc[u][3] + beta * svv[3];
    o1.x = alpha * acc[u][4] + beta * svv[4];
    o1.y = alpha * acc[u][5] + beta * svv[5];
    o1.z = alpha * acc[u][6] + beta * svv[6];
    o1.w = alpha * acc[u][7] + beta * svv[7];
    float* po = o + ((long)b * Nn + n) * Cc + h * HDd + ty * 8;
    *(float4*)po = o0;
    *(float4*)(po + 4) = o1;
  }
}

extern "C" void kernel_launch(void* const* d_in, const int* in_sizes, int n_in,
                              void* d_out, int out_size, void* d_ws, size_t ws_size,
                              hipStream_t stream) {
  const float* q    = (const float*)d_in[0];
  const float* kv   = (const float*)d_in[1];
  const float* Wq   = (const float*)d_in[2];
  const float* Wkv  = (const float*)d_in[3];
  const float* Wp   = (const float*)d_in[4];
  const float* bp   = (const float*)d_in[5];
  const float* rpb  = (const float*)d_in[6];
  const float* Wexp = (const float*)d_in[7];
  const float* g1   = (const float*)d_in[8];
  const float* b1   = (const float*)d_in[9];
  const float* Wdw  = (const float*)d_in[10];
  const float* g2   = (const float*)d_in[11];
  const float* b2   = (const float*)d_in[12];
  const float* Wred = (const float*)d_in[13];
  const float* g3   = (const float*)d_in[14];
  const float* b3   = (const float*)d_in[15];
  float* out = (float*)d_out;

  float* ws = (float*)d_ws;
  size_t off = 0;
  auto alloc = [&](size_t n) { float* p = ws + off; off += n; return p; };
  float* attn   = alloc((size_t)Bb * NHh * NMs);        // 134.2 MB (reused for a2)
  float* x1n    = alloc((size_t)CHUNK * HIDh * NMs);    // 100.7 MB
  float* qh     = alloc((size_t)Bb * NHh * Nn * HDd);   // 16.8 MB (reused for o)
  float* kbuf   = alloc((size_t)Bb * NHh * Mm * HDd);   // 4.2 MB
  float* vbuf   = alloc((size_t)Bb * NHh * Mm * HDd);   // 4.2 MB
  float* sv     = alloc((size_t)Bb * NHh * HDd);
  float* stats1 = alloc(Bb * 6);
  float* stats2c= alloc((size_t)Bb * HIDh * 2);
  float* stats3 = alloc(Bb * 2);
  float* o = qh;

  hipMemsetAsync(stats1, 0, (size_t)(Bb * 6 + Bb * HIDh * 2 + Bb * 2) * sizeof(float), stream);

  gemm_tn<0><<<dim3(Nn / 64, Cc / 64, Bb), 256, 0, stream>>>(
      q, Wq, nullptr, qh, nullptr, Cc, (long)Cc * Nn, Nn, 1);
  gemm_tn<1><<<dim3(Mm / 64, 512 / 64, Bb), 256, 0, stream>>>(
      kv, Wkv, nullptr, kbuf, vbuf, Cc, (long)Cc * Mm, Mm, 1);
  compute_sv<<<dim3(Bb * NHh), 256, 0, stream>>>(vbuf, sv);
  attn_softmax<<<dim3(Nn / 32, NHh, Bb), 256, 0, stream>>>(qh, kbuf, rpb, attn);

  for (int b0 = 0; b0 < Bb; b0 += CHUNK) {
    expand_stats<<<dim3(NMs / 1024, CHUNK), 256, 0, stream>>>(attn, Wexp, stats1, b0);
    expand_norm<<<dim3(NMs / 256, CHUNK), 256, 0, stream>>>(attn, Wexp, g1, b1, stats1, x1n, b0);
    dwconv_stats<<<dim3(Nn / 16, CHUNK * HIDh), 256, 0, stream>>>(x1n, Wdw, stats2c, b0);
    dwconv_fuse<<<dim3(Nn / 8, CHUNK), 256, 0, stream>>>(
        x1n, Wdw, g2, b2, Wred, stats2c, attn, stats3, b0);
  }

  pv_out<<<dim3(Nn / 256, NHh, Bb), 256, 0, stream>>>(attn, vbuf, sv, stats3, g3, b3, o);
  gemm_tn<2><<<dim3(Nn / 64, Cc / 64, Bb), 256, 0, stream>>>(
      o, Wp, bp, out, nullptr, Cc, (long)Nn * Cc, 1, Cc);
}

// Round 3
// 753.906 us; speedup vs baseline: 1.6124x; 1.0581x over previous
//
#include <hip/hip_runtime.h>
#include <math.h>

#define Bb 16
#define Cc 256
#define Nn 1024
#define Mm 256
#define NHh 8
#define HDd 32
#define HIDh 24
#define NMs (Nn*Mm)
#define TT 16
#define EPSf 1e-5f
#define SCALEf 0.17677669529663687f   // 1/sqrt(32)

__device__ __forceinline__ float wave_sum(float v){
#pragma unroll
  for (int off=32; off; off>>=1) v += __shfl_xor(v, off, 64);
  return v;
}
__device__ __forceinline__ float wave_max(float v){
#pragma unroll
  for (int off=32; off; off>>=1) v = fmaxf(v, __shfl_xor(v, off, 64));
  return v;
}
__device__ __forceinline__ float swish_(float x){ return x / (1.f + __expf(-x)); }
__device__ __forceinline__ unsigned short f2bf(float f){
  unsigned u = __float_as_uint(f);
  u += 0x7fffu + ((u >> 16) & 1u);          // round-to-nearest-even
  return (unsigned short)(u >> 16);
}
__device__ __forceinline__ float bflo(unsigned u){ return __uint_as_float(u << 16); }
__device__ __forceinline__ float bfhi(unsigned u){ return __uint_as_float(u & 0xffff0000u); }

// ------------- GEMM: out[b,i,j] = sum_k A[b,k,i]*W[j,k] (+bias) -------------
template<int MODE>
__launch_bounds__(256)
__global__ void gemm_tn(const float* __restrict__ A, const float* __restrict__ W,
                        const float* __restrict__ bias, float* __restrict__ O1,
                        float* __restrict__ O2, int Kdim, long sAb, int sAk, int sAi)
{
  __shared__ __align__(16) float As[16][68];
  __shared__ __align__(16) float Ws[16][68];
  const int b  = blockIdx.z;
  const int i0 = blockIdx.x * 64;
  const int j0 = blockIdx.y * 64;
  const int tid = threadIdx.x;
  const int tx = tid & 15, ty = tid >> 4;
  const float* Ab = A + (long)b * sAb;
  float acc[4][4] = {};
  for (int k0 = 0; k0 < Kdim; k0 += 16) {
#pragma unroll
    for (int t = 0; t < 4; t++) {
      int idx = tid + t * 256;
      int kk, ii;
      if (sAi == 1) { kk = idx >> 6; ii = idx & 63; }
      else          { ii = idx >> 4; kk = idx & 15; }
      As[kk][ii] = Ab[(long)(k0 + kk) * sAk + (long)(i0 + ii) * sAi];
    }
#pragma unroll
    for (int t = 0; t < 4; t++) {
      int idx = tid + t * 256;
      int jj = idx & 63, kk = idx >> 6;
      Ws[kk][jj] = W[(long)(j0 + jj) * Kdim + (k0 + kk)];
    }
    __syncthreads();
#pragma unroll
    for (int kk = 0; kk < 16; kk++) {
      const float4 av = *(const float4*)&As[kk][tx * 4];
      const float4 wv = *(const float4*)&Ws[kk][ty * 4];
      const float a4[4] = {av.x, av.y, av.z, av.w};
      const float w4[4] = {wv.x, wv.y, wv.z, wv.w};
#pragma unroll
      for (int u = 0; u < 4; u++)
#pragma unroll
        for (int v = 0; v < 4; v++)
          acc[u][v] = fmaf(a4[u], w4[v], acc[u][v]);
    }
    __syncthreads();
  }
#pragma unroll
  for (int u = 0; u < 4; u++) {
    const int i = i0 + tx * 4 + u;
#pragma unroll
    for (int v = 0; v < 4; v++) {
      const int j = j0 + ty * 4 + v;
      float val = acc[u][v];
      if (MODE == 0) {
        int h = j >> 5, d = j & 31;
        O1[(((long)b * NHh + h) * Nn + i) * HDd + d] = val;
      } else if (MODE == 1) {
        int two = j >> 8, jj = j & 255;
        int h = jj >> 5, d = jj & 31;
        float* p = two ? O2 : O1;
        p[(((long)b * NHh + h) * Mm + i) * HDd + d] = val;
      } else {
        O1[((long)b * Cc + j) * Nn + i] = val + bias[j];
      }
    }
  }
}

// ------------- sv[b,h,d] = sum_m v[b,h,m,d] -------------
__launch_bounds__(256)
__global__ void compute_sv(const float* __restrict__ vb, float* __restrict__ sv)
{
  __shared__ float red[256];
  const int bh = blockIdx.x, tid = threadIdx.x;
  const int d = tid & 31, ch = tid >> 5;
  const float* vp = vb + (long)bh * Mm * HDd;
  float s = 0.f;
  for (int m = ch; m < Mm; m += 8) s += vp[m * HDd + d];
  red[tid] = s;
  __syncthreads();
  if (tid < 32) {
    float t = 0.f;
#pragma unroll
    for (int cc = 0; cc < 8; cc++) t += red[cc * 32 + tid];
    sv[(long)bh * HDd + tid] = t;
  }
}

// ------------- scores + softmax: attn[b,h,n,m] -------------
__launch_bounds__(256)
__global__ void attn_softmax(const float* __restrict__ qh, const float* __restrict__ kb,
                             const float* __restrict__ rpb, float* __restrict__ attn)
{
  __shared__ __align__(16) float Ks[Mm][36];
  __shared__ __align__(16) float qs[32][36];
  const int b = blockIdx.z, h = blockIdx.y, n0 = blockIdx.x * 32;
  const int tid = threadIdx.x;
  const float* kp = kb + ((long)b * NHh + h) * Mm * HDd;
#pragma unroll
  for (int u = 0; u < 8; u++) {
    const int f = tid + u * 256;
    const int m = f >> 3, d = (f & 7) * 4;
    *(float4*)&Ks[m][d] = *(const float4*)&kp[m * HDd + d];
  }
  const float* qp = qh + (((long)b * NHh + h) * Nn + n0) * HDd;
#pragma unroll
  for (int u = 0; u < 4; u++) {
    const int idx = tid + u * 256;
    qs[idx >> 5][idx & 31] = qp[idx];
  }
  __syncthreads();
  const int lane = tid & 63, w = tid >> 6;
  const int r0 = w * 8;
  float s[8][4] = {};
#pragma unroll
  for (int dq = 0; dq < 8; dq++) {
    float4 k4[4];
#pragma unroll
    for (int j = 0; j < 4; j++) k4[j] = *(const float4*)&Ks[lane + j * 64][dq * 4];
#pragma unroll
    for (int r = 0; r < 8; r++) {
      const float4 q4 = *(const float4*)&qs[r0 + r][dq * 4];
#pragma unroll
      for (int j = 0; j < 4; j++) {
        s[r][j] = fmaf(q4.x, k4[j].x, s[r][j]);
        s[r][j] = fmaf(q4.y, k4[j].y, s[r][j]);
        s[r][j] = fmaf(q4.z, k4[j].z, s[r][j]);
        s[r][j] = fmaf(q4.w, k4[j].w, s[r][j]);
      }
    }
  }
#pragma unroll
  for (int r = 0; r < 8; r++) {
    const int n = n0 + r0 + r;
    const float* rp = rpb + (long)n * Mm;
    float sc[4];
#pragma unroll
    for (int j = 0; j < 4; j++) sc[j] = fmaf(s[r][j], SCALEf, rp[lane + j * 64]);
    float mx = fmaxf(fmaxf(sc[0], sc[1]), fmaxf(sc[2], sc[3]));
    mx = wave_max(mx);
    float e[4], sum = 0.f;
#pragma unroll
    for (int j = 0; j < 4; j++) { e[j] = __expf(sc[j] - mx); sum += e[j]; }
    sum = wave_sum(sum);
    const float inv = 1.f / sum;
    float* ap = attn + (((long)b * NHh + h) * Nn + n) * Mm;
#pragma unroll
    for (int j = 0; j < 4; j++) ap[lane + j * 64] = e[j] * inv;
  }
}

// ------------- stats1: gn1 sum/sumsq per (b,group) over expand output -------------
__launch_bounds__(256)
__global__ void expand_stats(const float* __restrict__ attn, const float* __restrict__ Wexp,
                             float* __restrict__ stats1)
{
  __shared__ float we[HIDh][NHh];
  __shared__ float red6[6][4];
  const int tid = threadIdx.x;
  const int b = blockIdx.y;
  if (tid < HIDh * NHh) ((float*)we)[tid] = Wexp[tid];
  __syncthreads();
  const float* ab = attn + (long)b * NHh * NMs;
  float s[3] = {}, sq[3] = {};
  for (int t = 0; t < 4; t++) {
    const long p = (long)blockIdx.x * 1024 + t * 256 + tid;
    float a[NHh];
#pragma unroll
    for (int h = 0; h < NHh; h++) a[h] = ab[(long)h * NMs + p];
#pragma unroll
    for (int c = 0; c < HIDh; c++) {
      float x = 0.f;
#pragma unroll
      for (int h = 0; h < NHh; h++) x = fmaf(we[c][h], a[h], x);
      s[c >> 3] += x; sq[c >> 3] = fmaf(x, x, sq[c >> 3]);
    }
  }
  const int lane = tid & 63, wid = tid >> 6;
#pragma unroll
  for (int g = 0; g < 3; g++) {
    float vs = wave_sum(s[g]);
    float vq = wave_sum(sq[g]);
    if (lane == 0) { red6[g * 2][wid] = vs; red6[g * 2 + 1][wid] = vq; }
  }
  __syncthreads();
  if (tid < 6) {
    float t = red6[tid][0] + red6[tid][1] + red6[tid][2] + red6[tid][3];
    atomicAdd(&stats1[b * 6 + tid], t);
  }
}

// ------------- pass B: recompute expand+gn1+swish, conv 3x3 -> gn2 stats -------------
// 8 waves x 3 channels; lane owns 4-m strip; rolling vertical conv state.
__launch_bounds__(512)
__global__ void dla_pass_b(const float* __restrict__ attn, const float* __restrict__ Wexp,
                           const float* __restrict__ g1, const float* __restrict__ b1,
                           const float* __restrict__ stats1, const float* __restrict__ Wdw,
                           float* __restrict__ stats2c)
{
  const int tid = threadIdx.x;
  const int wv = tid >> 6, lane = tid & 63;
  const int b = blockIdx.y;
  const int n0 = blockIdx.x * TT;
  const int c0 = wv * 3;
  float we[3][8], wd[3][9], A1[3], B1[3];
#pragma unroll
  for (int j = 0; j < 3; j++) {
    const int c = c0 + j;
#pragma unroll
    for (int h = 0; h < NHh; h++) we[j][h] = Wexp[c * NHh + h];
#pragma unroll
    for (int k = 0; k < 9; k++) wd[j][k] = Wdw[c * 9 + k];
    const int g = c >> 3;
    const float cnt = 8.f * NMs;
    const float mu = stats1[b * 6 + g * 2] / cnt;
    const float var = stats1[b * 6 + g * 2 + 1] / cnt - mu * mu;
    const float rs = rsqrtf(var + EPSf);
    A1[j] = rs * g1[c];
    B1[j] = b1[c] - mu * A1[j];
  }
  float s1[3][4] = {}, s2[3][4] = {};
  float sm[3] = {}, sq[3] = {};
  const float* ab = attn + (long)b * NHh * NMs;
  for (int r = -1; r <= TT; r++) {
    const int nn = n0 + r;
    const bool valid = (nn >= 0 && nn < Nn);
    float a_[NHh][4];
    if (valid) {
#pragma unroll
      for (int h = 0; h < NHh; h++) {
        const float4 t = *(const float4*)&ab[(long)h * NMs + (long)nn * Mm + lane * 4];
        a_[h][0] = t.x; a_[h][1] = t.y; a_[h][2] = t.z; a_[h][3] = t.w;
      }
    }
#pragma unroll
    for (int j = 0; j < 3; j++) {
      float x1[4];
      if (valid) {
#pragma unroll
        for (int mi = 0; mi < 4; mi++) {
          float x = 0.f;
#pragma unroll
          for (int h = 0; h < NHh; h++) x = fmaf(we[j][h], a_[h][mi], x);
          const float xn = fmaf(x, A1[j], B1[j]);
          x1[mi] = swish_(xn);
        }
      } else {
#pragma unroll
        for (int mi = 0; mi < 4; mi++) x1[mi] = 0.f;
      }
      float xl = __shfl_up(x1[3], 1);
      float xr = __shfl_down(x1[0], 1);
      if (lane == 0) xl = 0.f;
      if (lane == 63) xr = 0.f;
      const float L[4]  = {xl, x1[0], x1[1], x1[2]};
      const float Ce[4] = {x1[0], x1[1], x1[2], x1[3]};
      const float R[4]  = {x1[1], x1[2], x1[3], xr};
#pragma unroll
      for (int mi = 0; mi < 4; mi++) {
        const float u0 = wd[j][0]*L[mi] + wd[j][1]*Ce[mi] + wd[j][2]*R[mi];
        const float u1 = wd[j][3]*L[mi] + wd[j][4]*Ce[mi] + wd[j][5]*R[mi];
        const float u2 = wd[j][6]*L[mi] + wd[j][7]*Ce[mi] + wd[j][8]*R[mi];
        if (r >= 1) {
          const float y = s2[j][mi] + u2;
          sm[j] += y; sq[j] = fmaf(y, y, sq[j]);
        }
        s2[j][mi] = s1[j][mi] + u1;
        s1[j][mi] = u0;
      }
    }
  }
#pragma unroll
  for (int j = 0; j < 3; j++) {
    const float vs = wave_sum(sm[j]);
    const float vq = wave_sum(sq[j]);
    if (lane == 0) {
      atomicAdd(&stats2c[((long)b * HIDh + c0 + j) * 2], vs);
      atomicAdd(&stats2c[((long)b * HIDh + c0 + j) * 2 + 1], vq);
    }
  }
}

// ------------- pass C: recompute + gn2+swish + 1x1 reduce -> a2(bf16) + gn3 stats ----
__launch_bounds__(512)
__global__ void dla_pass_c(const float* __restrict__ attn, const float* __restrict__ Wexp,
                           const float* __restrict__ g1, const float* __restrict__ b1,
                           const float* __restrict__ stats1, const float* __restrict__ Wdw,
                           const float* __restrict__ g2, const float* __restrict__ b2,
                           const float* __restrict__ stats2c, const float* __restrict__ Wred,
                           unsigned short* __restrict__ a2, float* __restrict__ stats3)
{
  __shared__ float partial[8][NHh][Mm];
  __shared__ float red2[2][8];
  const int tid = threadIdx.x;
  const int wv = tid >> 6, lane = tid & 63;
  const int b = blockIdx.y;
  const int n0 = blockIdx.x * TT;
  const int c0 = wv * 3;
  float we[3][8], wd[3][9], wr[3][8], A1[3], B1[3], A2[3], B2[3];
#pragma unroll
  for (int j = 0; j < 3; j++) {
    const int c = c0 + j;
#pragma unroll
    for (int h = 0; h < NHh; h++) we[j][h] = Wexp[c * NHh + h];
#pragma unroll
    for (int k = 0; k < 9; k++) wd[j][k] = Wdw[c * 9 + k];
#pragma unroll
    for (int h = 0; h < NHh; h++) wr[j][h] = Wred[h * HIDh + c];
    const int g = c >> 3;
    const float cnt = 8.f * NMs;
    {
      const float mu = stats1[b * 6 + g * 2] / cnt;
      const float var = stats1[b * 6 + g * 2 + 1] / cnt - mu * mu;
      const float rs = rsqrtf(var + EPSf);
      A1[j] = rs * g1[c];
      B1[j] = b1[c] - mu * A1[j];
    }
    {
      float s = 0.f, q = 0.f;
#pragma unroll
      for (int cc = 0; cc < 8; cc++) {
        s += stats2c[((long)b * HIDh + g * 8 + cc) * 2];
        q += stats2c[((long)b * HIDh + g * 8 + cc) * 2 + 1];
      }
      const float mu = s / cnt;
      const float var = q / cnt - mu * mu;
      const float rs = rsqrtf(var + EPSf);
      A2[j] = rs * g2[c];
      B2[j] = b2[c] - mu * A2[j];
    }
  }
  float s1[3][4] = {}, s2[3][4] = {};
  float s3 = 0.f, q3 = 0.f;
  const float* ab = attn + (long)b * NHh * NMs;
  for (int r = -1; r <= TT; r++) {
    const int nn = n0 + r;
    const bool valid = (nn >= 0 && nn < Nn);
    float a_[NHh][4];
    if (valid) {
#pragma unroll
      for (int h = 0; h < NHh; h++) {
        const float4 t = *(const float4*)&ab[(long)h * NMs + (long)nn * Mm + lane * 4];
        a_[h][0] = t.x; a_[h][1] = t.y; a_[h][2] = t.z; a_[h][3] = t.w;
      }
    }
    float red[NHh][4];
    if (r >= 1) {
#pragma unroll
      for (int h = 0; h < NHh; h++)
#pragma unroll
        for (int mi = 0; mi < 4; mi++) red[h][mi] = 0.f;
    }
#pragma unroll
    for (int j = 0; j < 3; j++) {
      float x1[4];
      if (valid) {
#pragma unroll
        for (int mi = 0; mi < 4; mi++) {
          float x = 0.f;
#pragma unroll
          for (int h = 0; h < NHh; h++) x = fmaf(we[j][h], a_[h][mi], x);
          const float xn = fmaf(x, A1[j], B1[j]);
          x1[mi] = swish_(xn);
        }
      } else {
#pragma unroll
        for (int mi = 0; mi < 4; mi++) x1[mi] = 0.f;
      }
      float xl = __shfl_up(x1[3], 1);
      float xr = __shfl_down(x1[0], 1);
      if (lane == 0) xl = 0.f;
      if (lane == 63) xr = 0.f;
      const float L[4]  = {xl, x1[0], x1[1], x1[2]};
      const float Ce[4] = {x1[0], x1[1], x1[2], x1[3]};
      const float R[4]  = {x1[1], x1[2], x1[3], xr};
#pragma unroll
      for (int mi = 0; mi < 4; mi++) {
        const float u0 = wd[j][0]*L[mi] + wd[j][1]*Ce[mi] + wd[j][2]*R[mi];
        const float u1 = wd[j][3]*L[mi] + wd[j][4]*Ce[mi] + wd[j][5]*R[mi];
        const float u2 = wd[j][6]*L[mi] + wd[j][7]*Ce[mi] + wd[j][8]*R[mi];
        if (r >= 1) {
          const float y = s2[j][mi] + u2;
          const float xn2 = fmaf(y, A2[j], B2[j]);
          const float sw = swish_(xn2);
#pragma unroll
          for (int h = 0; h < NHh; h++) red[h][mi] = fmaf(wr[j][h], sw, red[h][mi]);
        }
        s2[j][mi] = s1[j][mi] + u1;
        s1[j][mi] = u0;
      }
    }
    if (r >= 1) {
      __syncthreads();   // previous row's sum-phase reads complete
#pragma unroll
      for (int h = 0; h < NHh; h++)
        *(float4*)&partial[wv][h][lane * 4] =
            make_float4(red[h][0], red[h][1], red[h][2], red[h][3]);
      __syncthreads();
      float v0 = 0.f, v1 = 0.f, v2 = 0.f, v3 = 0.f;
#pragma unroll
      for (int w = 0; w < 8; w++) {
        const float4 p = *(const float4*)&partial[w][wv][lane * 4];
        v0 += p.x; v1 += p.y; v2 += p.z; v3 += p.w;
      }
      const int n = n0 + r - 1;
      ushort4 st;
      st.x = f2bf(v0); st.y = f2bf(v1); st.z = f2bf(v2); st.w = f2bf(v3);
      *(ushort4*)&a2[(((long)b * NHh + wv) * Nn + n) * Mm + lane * 4] = st;
      s3 += v0 + v1 + v2 + v3;
      q3 = fmaf(v0, v0, q3); q3 = fmaf(v1, v1, q3);
      q3 = fmaf(v2, v2, q3); q3 = fmaf(v3, v3, q3);
    }
  }
  const float vs = wave_sum(s3);
  const float vq = wave_sum(q3);
  if (lane == 0) { red2[0][wv] = vs; red2[1][wv] = vq; }
  __syncthreads();
  if (tid < 2) {
    float t = 0.f;
#pragma unroll
    for (int w = 0; w < 8; w++) t += red2[tid][w];
    atomicAdd(&stats3[b * 2 + tid], t);
  }
}

// ------------- pv_out: gn3 (folded affine) + PV, A in bf16 -------------
__launch_bounds__(256)
__global__ void pv_out(const unsigned short* __restrict__ a2, const float* __restrict__ vb,
                       const float* __restrict__ sv, const float* __restrict__ stats3,
                       const float* __restrict__ g3, const float* __restrict__ b3,
                       float* __restrict__ o)
{
  __shared__ __align__(16) float As[16 * 260];
  __shared__ __align__(16) float Vs[Mm * HDd];
  const int b = blockIdx.z, h = blockIdx.y, n0 = blockIdx.x * 256;
  const int tid = threadIdx.x;
  const float* vp = vb + ((long)b * NHh + h) * Mm * HDd;
#pragma unroll
  for (int u = 0; u < 8; u++) {
    const int f = tid + u * 256;
    ((float4*)Vs)[f] = ((const float4*)vp)[f];
  }
  const unsigned short* ap = a2 + (((long)b * NHh + h) * Nn + n0) * Mm;
  const int tx = tid & 63, ty = tid >> 6;
  float acc[4][8] = {};
  for (int k0 = 0; k0 < Mm; k0 += 16) {
    __syncthreads();
#pragma unroll
    for (int u = 0; u < 2; u++) {
      const int s = tid + u * 256;
      const int row = s >> 1, half = (s & 1) * 8;
      const uint4 pk = *(const uint4*)(ap + (long)row * Mm + k0 + half);
      As[(half + 0) * 260 + row] = bflo(pk.x);
      As[(half + 1) * 260 + row] = bfhi(pk.x);
      As[(half + 2) * 260 + row] = bflo(pk.y);
      As[(half + 3) * 260 + row] = bfhi(pk.y);
      As[(half + 4) * 260 + row] = bflo(pk.z);
      As[(half + 5) * 260 + row] = bfhi(pk.z);
      As[(half + 6) * 260 + row] = bflo(pk.w);
      As[(half + 7) * 260 + row] = bfhi(pk.w);
    }
    __syncthreads();
#pragma unroll
    for (int k = 0; k < 16; k++) {
      const float4 a4 = *(const float4*)&As[k * 260 + tx * 4];
      const float4 w0 = *(const float4*)&Vs[(k0 + k) * HDd + ty * 8];
      const float4 w1 = *(const float4*)&Vs[(k0 + k) * HDd + ty * 8 + 4];
      const float av[4] = {a4.x, a4.y, a4.z, a4.w};
      const float vv[8] = {w0.x, w0.y, w0.z, w0.w, w1.x, w1.y, w1.z, w1.w};
#pragma unroll
      for (int u = 0; u < 4; u++)
#pragma unroll
        for (int v = 0; v < 8; v++)
          acc[u][v] = fmaf(av[u], vv[v], acc[u][v]);
    }
  }
  const float cnt = (float)(NHh * NMs);
  const float mu = stats3[b * 2] / cnt;
  const float var = stats3[b * 2 + 1] / cnt - mu * mu;
  const float r3 = rsqrtf(var + EPSf);
  const float alpha = r3 * g3[h];
  const float beta = b3[h] - mu * alpha;
  float svv[8];
#pragma unroll
  for (int v = 0; v < 8; v++) svv[v] = sv[((long)b * NHh + h) * HDd + ty * 8 + v];
#pragma unroll
  for (int u = 0; u < 4; u++) {
    const int n = n0 + tx * 4 + u;
    float4 o0, o1;
    o0.x = alpha * acc[u][0] + beta * svv[0];
    o0.y = alpha * acc[u][1] + beta * svv[1];
    o0.z = alpha * acc[u][2] + beta * svv[2];
    o0.w = alpha * acc[u][3] + beta * svv[3];
    o1.x = alpha * acc[u][4] + beta * svv[4];
    o1.y = alpha * acc[u][5] + beta * svv[5];
    o1.z = alpha * acc[u][6] + beta * svv[6];
    o1.w = alpha * acc[u][7] + beta * svv[7];
    float* po = o + ((long)b * Nn + n) * Cc + h * HDd + ty * 8;
    *(float4*)po = o0;
    *(float4*)(po + 4) = o1;
  }
}

extern "C" void kernel_launch(void* const* d_in, const int* in_sizes, int n_in,
                              void* d_out, int out_size, void* d_ws, size_t ws_size,
                              hipStream_t stream) {
  const float* q    = (const float*)d_in[0];
  const float* kv   = (const float*)d_in[1];
  const float* Wq   = (const float*)d_in[2];
  const float* Wkv  = (const float*)d_in[3];
  const float* Wp   = (const float*)d_in[4];
  const float* bp   = (const float*)d_in[5];
  const float* rpb  = (const float*)d_in[6];
  const float* Wexp = (const float*)d_in[7];
  const float* g1   = (const float*)d_in[8];
  const float* b1   = (const float*)d_in[9];
  const float* Wdw  = (const float*)d_in[10];
  const float* g2   = (const float*)d_in[11];
  const float* b2   = (const float*)d_in[12];
  const float* Wred = (const float*)d_in[13];
  const float* g3   = (const float*)d_in[14];
  const float* b3   = (const float*)d_in[15];
  float* out = (float*)d_out;

  float* ws = (float*)d_ws;
  size_t off = 0;
  auto alloc = [&](size_t n) { float* p = ws + off; off += n; return p; };
  float* attn     = alloc((size_t)Bb * NHh * NMs);        // 134.2 MB
  float* a2f      = alloc((size_t)Bb * NHh * NMs / 2);    // 67.1 MB as bf16
  float* qh       = alloc((size_t)Bb * NHh * Nn * HDd);   // 16.8 MB (reused for o)
  float* kbuf     = alloc((size_t)Bb * NHh * Mm * HDd);   // 4.2 MB
  float* vbuf     = alloc((size_t)Bb * NHh * Mm * HDd);   // 4.2 MB
  float* sv       = alloc((size_t)Bb * NHh * HDd);
  float* stats1   = alloc(Bb * 6);
  float* stats2c  = alloc((size_t)Bb * HIDh * 2);
  float* stats3   = alloc(Bb * 2);
  unsigned short* a2 = (unsigned short*)a2f;
  float* o = qh;

  hipMemsetAsync(stats1, 0, (size_t)(Bb * 6 + Bb * HIDh * 2 + Bb * 2) * sizeof(float), stream);

  gemm_tn<0><<<dim3(Nn / 64, Cc / 64, Bb), 256, 0, stream>>>(
      q, Wq, nullptr, qh, nullptr, Cc, (long)Cc * Nn, Nn, 1);
  gemm_tn<1><<<dim3(Mm / 64, 512 / 64, Bb), 256, 0, stream>>>(
      kv, Wkv, nullptr, kbuf, vbuf, Cc, (long)Cc * Mm, Mm, 1);
  compute_sv<<<dim3(Bb * NHh), 256, 0, stream>>>(vbuf, sv);
  attn_softmax<<<dim3(Nn / 32, NHh, Bb), 256, 0, stream>>>(qh, kbuf, rpb, attn);

  expand_stats<<<dim3(NMs / 1024, Bb), 256, 0, stream>>>(attn, Wexp, stats1);
  dla_pass_b<<<dim3(Nn / TT, Bb), 512, 0, stream>>>(
      attn, Wexp, g1, b1, stats1, Wdw, stats2c);
  dla_pass_c<<<dim3(Nn / TT, Bb), 512, 0, stream>>>(
      attn, Wexp, g1, b1, stats1, Wdw, g2, b2, stats2c, Wred, a2, stats3);

  pv_out<<<dim3(Nn / 256, NHh, Bb), 256, 0, stream>>>(a2, vbuf, sv, stats3, g3, b3, o);
  gemm_tn<2><<<dim3(Nn / 64, Cc / 64, Bb), 256, 0, stream>>>(
      o, Wp, bp, out, nullptr, Cc, (long)Nn * Cc, 1, Cc);
}